// Round 3
// baseline (231.985 us; speedup 1.0000x reference)
//
#include <hip/hip_runtime.h>

#define NP 8
#define TPB 256

// Fused CIoU: one kernel, zero LDS clip buffers, zero scratch.
// Intersection area via Green's theorem on clipped edges:
//   area(A∩B) = 1/2 [ sum_{edges of A} cross(P(t0),P(t1)) clipped to B
//             + sum_{edges of B} cross(P(t0),P(t1)) clipped to A ]
// Each edge's [t0,t1] found by 8 branchless half-plane interval updates.
__global__ __launch_bounds__(TPB, 4) void ciou_fused(
    const float* __restrict__ A,
    const float* __restrict__ Bq,
    float* __restrict__ out,
    double* __restrict__ acc,
    unsigned int* __restrict__ cnt,
    int nbatch, int nblocks)
{
    const int t = threadIdx.x;
    const int i = blockIdx.x * TPB + t;
    float val = 0.f;

    if (i < nbatch) {
        float ax[NP], ay[NP], bx[NP], by[NP];
        const float4* pa = (const float4*)(A + (size_t)i * (2 * NP));
        const float4* pb = (const float4*)(Bq + (size_t)i * (2 * NP));
        #pragma unroll
        for (int j = 0; j < NP / 2; ++j) {
            float4 v0 = pa[j];
            ax[2*j] = v0.x; ay[2*j] = v0.y; ax[2*j+1] = v0.z; ay[2*j+1] = v0.w;
            float4 v1 = pb[j];
            bx[2*j] = v1.x; by[2*j] = v1.y; bx[2*j+1] = v1.z; by[2*j+1] = v1.w;
        }

        // Edge vectors (input order is CCW; sort_poly is a pure rotation).
        float dax[NP], day[NP], dbx[NP], dby[NP];
        #pragma unroll
        for (int j = 0; j < NP; ++j) {
            int k = (j + 1) & (NP - 1);
            dax[j] = ax[k] - ax[j]; day[j] = ay[k] - ay[j];
            dbx[j] = bx[k] - bx[j]; dby[j] = by[k] - by[j];
        }

        float area_a = 0.f, area_b = 0.f;
        #pragma unroll
        for (int j = 0; j < NP; ++j) {
            int k = (j + 1) & (NP - 1);
            area_a += ax[j] * ay[k] - ay[j] * ax[k];
            area_b += bx[j] * by[k] - by[j] * bx[k];
        }
        area_a *= 0.5f; area_b *= 0.5f;

        // ---- Intersection area: branchless edge-interval clipping ----
        float inter2 = 0.f;   // accumulates 2*area

        // A's edges clipped against B's half-planes
        #pragma unroll
        for (int e = 0; e < NP; ++e) {
            float Px = ax[e], Py = ay[e], Dx = dax[e], Dy = day[e];
            float t0 = 0.f, t1 = 1.f;
            bool empty = false;
            #pragma unroll
            for (int j = 0; j < NP; ++j) {
                // inside B: cross(E_B, p - V_B) >= 0  ->  a + t*b >= 0
                float a = dbx[j] * (Py - by[j]) - dby[j] * (Px - bx[j]);
                float b = dbx[j] * Dy - dby[j] * Dx;
                float tc = -a / b;              // inf/nan only when unused
                bool bp = b > 0.f, bn = b < 0.f;
                t0 = (bp && tc > t0) ? tc : t0;
                t1 = (bn && tc < t1) ? tc : t1;
                empty = empty || (!bp && !bn && a < 0.f);
            }
            t0 = fminf(fmaxf(t0, 0.f), 1.f);
            t1 = fminf(fmaxf(t1, 0.f), 1.f);
            bool ok = (t1 > t0) && !empty;
            float P0x = Px + t0 * Dx, P0y = Py + t0 * Dy;
            float P1x = Px + t1 * Dx, P1y = Py + t1 * Dy;
            float c = P0x * P1y - P0y * P1x;
            inter2 += ok ? c : 0.f;
        }
        // B's edges clipped against A's half-planes
        #pragma unroll
        for (int e = 0; e < NP; ++e) {
            float Px = bx[e], Py = by[e], Dx = dbx[e], Dy = dby[e];
            float t0 = 0.f, t1 = 1.f;
            bool empty = false;
            #pragma unroll
            for (int j = 0; j < NP; ++j) {
                float a = dax[j] * (Py - ay[j]) - day[j] * (Px - ax[j]);
                float b = dax[j] * Dy - day[j] * Dx;
                float tc = -a / b;
                bool bp = b > 0.f, bn = b < 0.f;
                t0 = (bp && tc > t0) ? tc : t0;
                t1 = (bn && tc < t1) ? tc : t1;
                empty = empty || (!bp && !bn && a < 0.f);
            }
            t0 = fminf(fmaxf(t0, 0.f), 1.f);
            t1 = fminf(fmaxf(t1, 0.f), 1.f);
            bool ok = (t1 > t0) && !empty;
            float P0x = Px + t0 * Dx, P0y = Py + t0 * Dy;
            float P1x = Px + t1 * Dx, P1y = Py + t1 * Dy;
            float c = P0x * P1y - P0y * P1x;
            inter2 += ok ? c : 0.f;
        }
        float inter = fmaxf(0.5f * inter2, 0.f);

        float uni = area_a + area_b - inter;
        float iou = inter / uni;

        // ---- Convex hull area of 16 points: register Jarvis march ----
        float stx = ax[0], sty = ay[0];
        {
            auto upd = [&](float px, float py) {
                bool b = (py < sty) || (py == sty && px < stx);
                stx = b ? px : stx; sty = b ? py : sty;
            };
            #pragma unroll
            for (int j = 1; j < NP; ++j) upd(ax[j], ay[j]);
            #pragma unroll
            for (int j = 0; j < NP; ++j) upd(bx[j], by[j]);
        }
        float cxv = stx, cyv = sty;
        float accH = 0.f;
        bool done = false;
        for (int it = 0; it < 16; ++it) {
            float nx = cxv, ny = cyv;
            float cdx = 0.f, cdy = 0.f;
            bool cv = false;
            auto scan = [&](float px, float py) {
                float vx = px - cxv, vy = py - cyv;
                bool valid = (vx * vx + vy * vy) > 1e-16f;
                float cr = cdx * vy - cdy * vx;   // p right of cur->cand?
                bool take = valid && (!cv || cr < 0.f);
                nx = take ? px : nx;  ny = take ? py : ny;
                cdx = take ? vx : cdx; cdy = take ? vy : cdy;
                cv = cv || valid;
            };
            #pragma unroll
            for (int j = 0; j < NP; ++j) scan(ax[j], ay[j]);
            #pragma unroll
            for (int j = 0; j < NP; ++j) scan(bx[j], by[j]);
            accH += done ? 0.f : (cxv * ny - cyv * nx);
            done = done || (nx == stx && ny == sty);
            cxv = nx; cyv = ny;
            if (__all(done)) break;
        }
        float ch = 0.5f * accH;

        val = iou - (ch - uni) / ch;
    }

    // ---- reduction: wave shuffle -> LDS(16B) -> global double atomic ----
    float v = val;
    #pragma unroll
    for (int off = 32; off > 0; off >>= 1) v += __shfl_down(v, off);
    __shared__ float wsum[4];
    int lane = t & 63, wid = t >> 6;
    if (lane == 0) wsum[wid] = v;
    __syncthreads();
    if (t == 0) {
        double bsum = (double)wsum[0] + (double)wsum[1]
                    + (double)wsum[2] + (double)wsum[3];
        atomicAdd(acc, bsum);
        __threadfence();
        unsigned int old = atomicAdd(cnt, 1u);
        if (old == (unsigned int)(nblocks - 1)) {
            double total = atomicAdd(acc, 0.0);   // serialized read-after-all
            out[0] = (float)(total / (double)nbatch);
        }
    }
}

extern "C" void kernel_launch(void* const* d_in, const int* in_sizes, int n_in,
                              void* d_out, int out_size, void* d_ws, size_t ws_size,
                              hipStream_t stream) {
    const float* a = (const float*)d_in[0];
    const float* b = (const float*)d_in[1];
    float* out = (float*)d_out;
    int nbatch = in_sizes[0] / (2 * NP);
    int nblocks = (nbatch + TPB - 1) / TPB;
    double* acc = (double*)d_ws;                       // [0,8): double sum
    unsigned int* cnt = (unsigned int*)((char*)d_ws + 8);  // [8,12): counter
    hipMemsetAsync(d_ws, 0, 16, stream);
    ciou_fused<<<nblocks, TPB, 0, stream>>>(a, b, out, acc, cnt, nbatch, nblocks);
}